// Round 6
// baseline (181.923 us; speedup 1.0000x reference)
//
#include <hip/hip_runtime.h>
#include <stdint.h>

// EMA along contiguous T axis — asm-enforced software pipeline.
// (Resubmission: R5 bench died in container acquisition, same infra error
// class as R2 which reran clean. Kernel re-audited: no hang path (vmcnt/
// lgkm waits can't deadlock; barriers uniform at ns=4), no OOB (round-5
// granule clamped), per-wave vmem ledger exact (6 loads + 6 stores, partial
// -exec store still issues).)
//
// R4 post-mortem: VGPR_Count=52 proved the compiler SANK the register
// prefetch to its use (12 in-flight float4 loads need >=48 VGPRs). Every
// prior round's prefetch was destroyed by the compiler (R1: legalizer
// vmcnt(0) drains; R3/R4: load sinking). All variants therefore ran the
// same load->wait->compute->store phase machine at ~50% memory duty
// (3.26 TB/s L2-side = 52% of the 6.3 TB/s copy ceiling).
//
// This version enforces the pipeline by hand (8-phase-GEMM discipline):
//  - ALL in-loop global loads are asm volatile global_load_dwordx4
//    (untracked by the waitcnt legalizer -> cannot be sunk or drained)
//  - hand vmcnt ledger: per wave per iter exactly 6 asm loads (seq s+1,
//    issued right after the deposit of seq s) + 6 normal stores; iter-top
//    queue is FIFO [L_s(6), S_(s-1)(6)] -> s_waitcnt vmcnt(6) is exact
//    (vmcnt retires in order); vmcnt(0) only at s==0
//  - stores stay normal C++ (stores never trigger compiler waitcnts);
//    no normal global LOADS exist in the loop (init/weights force-completed
//    in the prologue via a dummy asm use)
//  - raw s_barrier + manual lgkmcnt(0) for the waveB exchange (double-
//    buffered, one barrier/seq); never __syncthreads (it drains vmcnt)
//  - sched_barrier(0) fences pin every phase region (guide rule #18)
//  - tail granule: asm load address CLAMPED per-lane (safe duplicate read);
//    only the normal deposit/readback/store are predicated
// Math/layout identical to R4 (proven correct twice): CHW=28 padded LDS,
// wave-local staging, analytic-A scan.

constexpr int T_LEN = 6000;
constexpr int KPT   = 24;                 // elements per chunk (thread)
constexpr int NCH   = T_LEN / KPT;        // 250 chunks
constexpr int BLOCK = 256;                // 4 waves
constexpr int CHW   = 28;                 // padded words per chunk (112B, 16B-aligned)
constexpr int G4    = T_LEN / 4;          // 1500 float4 granules

typedef float f32x4 __attribute__((ext_vector_type(4)));

__device__ __forceinline__ void async_load4(f32x4& dst, const f32x4* p) {
    // Untracked vector load: compiler sees only a register def. The hand
    // vmcnt ledger (below) provides the wait; sched_barrier(0) fences
    // provide the ordering vs normal LDS/global ops.
    asm volatile("global_load_dwordx4 %0, %1, off" : "=&v"(dst) : "v"(p));
}

__global__ __launch_bounds__(BLOCK) void ema_kernel(
    const float* __restrict__ x, const float* __restrict__ init,
    const float* __restrict__ wptr, float* __restrict__ out, int nseq)
{
    __shared__ __align__(16) float lds[256 * CHW];   // 28672 B
    __shared__ float waveB[2][4];

    const int tid  = threadIdx.x;
    const int lane = tid & 63;
    const int wid  = tid >> 6;
    const int bid  = blockIdx.x;
    const int G    = gridDim.x;
    const int ns   = (nseq - bid + G - 1) / G;       // block-uniform; <=4
    if (ns <= 0) return;

    const float w = fminf(fmaxf(wptr[0], 0.0f), 1.0f);
    const float d = 1.0f - w;

    // ---- data-independent constants ----
    float pw8[8];                       // d^(j+1), j=0..7
    { float p = d;
      #pragma unroll
      for (int j = 0; j < 8; ++j) { pw8[j] = p; p *= d; } }
    const float d8 = pw8[7];            // d^8
    const float q  = d8 * d8 * d8;      // d^24: per-chunk decay
    float qp[8];                        // q^(2^k)
    qp[0] = q;
    #pragma unroll
    for (int k = 1; k < 8; ++k) qp[k] = qp[k-1] * qp[k-1];
    const float q64 = qp[6];
    float qlane = 1.0f;                 // q^lane
    #pragma unroll
    for (int k = 0; k < 6; ++k) if ((lane >> k) & 1) qlane *= qp[k];
    float qtid = qlane;                 // q^tid
    if (wid & 1) qtid *= qp[6];
    if (wid & 2) qtid *= qp[7];

    // ---- initial states (ns <= 4), forced complete BEFORE any asm load
    //      so no compiler-tracked vmem load/wait exists in the loop ----
    const float i0 = init[bid];
    const float i1 = (ns > 1) ? init[bid + G]     : 0.0f;
    const float i2 = (ns > 2) ? init[bid + 2 * G] : 0.0f;
    const float i3 = (ns > 3) ? init[bid + 3 * G] : 0.0f;
    asm volatile("" :: "v"(w), "v"(i0), "v"(i1), "v"(i2), "v"(i3));
    __builtin_amdgcn_sched_barrier(0);

    // ---- granule geometry: wave w owns granules [384w, 384w+384) ----
    // rounds 0..4 always valid (max g = 1152+63+256 = 1471 < 1500);
    // round 5 valid iff g0+320 < 1500 (only wave 3 lanes >= 28 invalid).
    const int g0  = wid * 384 + lane;
    int woff[6];
    #pragma unroll
    for (int i = 0; i < 6; ++i) {
        const int g = g0 + 64 * i;
        woff[i] = CHW * (g / 6) + 4 * (g % 6);   // <= 7160 < 7168: in-bounds
    }
    const int  g5  = g0 + 320;
    const bool ok5 = (g5 < G4);
    const int  g5c = ok5 ? g5 : (G4 - 1);        // clamped (safe dup read)
    const bool act   = (tid < NCH);
    const int  cbase = CHW * tid;

    // ---- prologue: issue L0 (6 asm loads; ledger starts at 6) ----
    f32x4 r0, r1, r2, r3, r4, r5;
    {
        const f32x4* b4 = (const f32x4*)(x + (size_t)bid * T_LEN);
        async_load4(r0, b4 + g0);
        async_load4(r1, b4 + g0 + 64);
        async_load4(r2, b4 + g0 + 128);
        async_load4(r3, b4 + g0 + 192);
        async_load4(r4, b4 + g0 + 256);
        async_load4(r5, b4 + g5c);
    }
    __builtin_amdgcn_sched_barrier(0);

    for (int s = 0; s < ns; ++s) {
        const int seq = bid + s * G;

        // ---- ledger wait: queue is [L_s(6), S_(s-1)(6)] (FIFO). ----
        if (s == 0) asm volatile("s_waitcnt vmcnt(0)");
        else        asm volatile("s_waitcnt vmcnt(6)");
        __builtin_amdgcn_sched_barrier(0);

        // ---- deposit L_s registers into padded LDS (wave-local) ----
        *(f32x4*)&lds[woff[0]] = r0;
        *(f32x4*)&lds[woff[1]] = r1;
        *(f32x4*)&lds[woff[2]] = r2;
        *(f32x4*)&lds[woff[3]] = r3;
        *(f32x4*)&lds[woff[4]] = r4;
        if (ok5) *(f32x4*)&lds[woff[5]] = r5;
        __builtin_amdgcn_sched_barrier(0);

        // ---- issue L_(s+1): in flight across chain+scan+fixup+stores ----
        if (s + 1 < ns) {
            const f32x4* n4 = (const f32x4*)(x + (size_t)(seq + G) * T_LEN);
            async_load4(r0, n4 + g0);
            async_load4(r1, n4 + g0 + 64);
            async_load4(r2, n4 + g0 + 128);
            async_load4(r3, n4 + g0 + 192);
            async_load4(r4, n4 + g0 + 256);
            async_load4(r5, n4 + g5c);
        }
        __builtin_amdgcn_sched_barrier(0);

        // ---- per-chunk prefix chain: B_j = d*B_{j-1} + w*x_j ----
        float Bv[KPT];
        float bagg = 0.0f;
        if (act) {
            const f32x4 c0 = *(const f32x4*)&lds[cbase];
            const f32x4 c1 = *(const f32x4*)&lds[cbase + 4];
            const f32x4 c2 = *(const f32x4*)&lds[cbase + 8];
            const f32x4 c3 = *(const f32x4*)&lds[cbase + 12];
            const f32x4 c4 = *(const f32x4*)&lds[cbase + 16];
            const f32x4 c5 = *(const f32x4*)&lds[cbase + 20];
            float xv[KPT];
            xv[0]=c0.x;  xv[1]=c0.y;  xv[2]=c0.z;  xv[3]=c0.w;
            xv[4]=c1.x;  xv[5]=c1.y;  xv[6]=c1.z;  xv[7]=c1.w;
            xv[8]=c2.x;  xv[9]=c2.y;  xv[10]=c2.z; xv[11]=c2.w;
            xv[12]=c3.x; xv[13]=c3.y; xv[14]=c3.z; xv[15]=c3.w;
            xv[16]=c4.x; xv[17]=c4.y; xv[18]=c4.z; xv[19]=c4.w;
            xv[20]=c5.x; xv[21]=c5.y; xv[22]=c5.z; xv[23]=c5.w;
            float acc = 0.0f;
            #pragma unroll
            for (int j = 0; j < KPT; ++j) { acc = fmaf(d, acc, w * xv[j]); Bv[j] = acc; }
            bagg = acc;
        }

        // ---- wave-level inclusive scan of chunk aggregates (A analytic) ----
        float b = bagg;
        #pragma unroll
        for (int k = 0; k < 6; ++k) {
            const float pb = __shfl_up(b, 1u << k, 64);
            if (lane >= (1 << k)) b = fmaf(qp[k], pb, b);
        }
        if (lane == 63) waveB[s & 1][wid] = b;

        // ---- cross-wave exchange: raw barrier, manual lgkm drain.
        //      NEVER __syncthreads (it emits vmcnt(0) and drains L_(s+1)).
        __builtin_amdgcn_sched_barrier(0);
        asm volatile("s_waitcnt lgkmcnt(0)");
        __builtin_amdgcn_s_barrier();
        __builtin_amdgcn_sched_barrier(0);

        const float wb0 = waveB[s & 1][0];
        const float wb1 = waveB[s & 1][1];
        const float wb2 = waveB[s & 1][2];
        float pB = 0.0f;
        if (wid > 0) pB = wb0;
        if (wid > 1) pB = fmaf(q64, pB, wb1);
        if (wid > 2) pB = fmaf(q64, pB, wb2);

        float eb = __shfl_up(b, 1, 64);
        if (lane == 0) eb = 0.0f;
        const float Bex  = fmaf(qlane, pB, eb);
        const float s0   = (s == 0) ? i0 : (s == 1) ? i1 : (s == 2) ? i2 : i3;
        const float sin_ = fmaf(qtid, s0, Bex);

        // ---- fixup out_j = d^(j+1)*sin + B_j, strided write (wave-local) ----
        if (act) {
            const float b0 = sin_;
            const float b1 = b0 * d8;
            const float b2 = b1 * d8;
            f32x4 oA = { fmaf(pw8[0],b0,Bv[0]),  fmaf(pw8[1],b0,Bv[1]),
                         fmaf(pw8[2],b0,Bv[2]),  fmaf(pw8[3],b0,Bv[3]) };
            f32x4 oB = { fmaf(pw8[4],b0,Bv[4]),  fmaf(pw8[5],b0,Bv[5]),
                         fmaf(pw8[6],b0,Bv[6]),  fmaf(pw8[7],b0,Bv[7]) };
            f32x4 oC = { fmaf(pw8[0],b1,Bv[8]),  fmaf(pw8[1],b1,Bv[9]),
                         fmaf(pw8[2],b1,Bv[10]), fmaf(pw8[3],b1,Bv[11]) };
            f32x4 oD = { fmaf(pw8[4],b1,Bv[12]), fmaf(pw8[5],b1,Bv[13]),
                         fmaf(pw8[6],b1,Bv[14]), fmaf(pw8[7],b1,Bv[15]) };
            f32x4 oE = { fmaf(pw8[0],b2,Bv[16]), fmaf(pw8[1],b2,Bv[17]),
                         fmaf(pw8[2],b2,Bv[18]), fmaf(pw8[3],b2,Bv[19]) };
            f32x4 oF = { fmaf(pw8[4],b2,Bv[20]), fmaf(pw8[5],b2,Bv[21]),
                         fmaf(pw8[6],b2,Bv[22]), fmaf(pw8[7],b2,Bv[23]) };
            *(f32x4*)&lds[cbase]      = oA;
            *(f32x4*)&lds[cbase + 4]  = oB;
            *(f32x4*)&lds[cbase + 8]  = oC;
            *(f32x4*)&lds[cbase + 12] = oD;
            *(f32x4*)&lds[cbase + 16] = oE;
            *(f32x4*)&lds[cbase + 20] = oF;
        }

        // ---- coalesced readback + normal stores (6 per wave, last
        //      predicated; stores never trigger compiler waitcnts) ----
        {
            f32x4* os4 = (f32x4*)(out + (size_t)seq * T_LEN);
            os4[g0]       = *(const f32x4*)&lds[woff[0]];
            os4[g0 + 64]  = *(const f32x4*)&lds[woff[1]];
            os4[g0 + 128] = *(const f32x4*)&lds[woff[2]];
            os4[g0 + 192] = *(const f32x4*)&lds[woff[3]];
            os4[g0 + 256] = *(const f32x4*)&lds[woff[4]];
            if (ok5) os4[g5] = *(const f32x4*)&lds[woff[5]];
        }
        __builtin_amdgcn_sched_barrier(0);
    }
}

extern "C" void kernel_launch(void* const* d_in, const int* in_sizes, int n_in,
                              void* d_out, int out_size, void* d_ws, size_t ws_size,
                              hipStream_t stream) {
    const float* mag_spec = (const float*)d_in[0];
    const float* initial_state = (const float*)d_in[1];
    const float* weights = (const float*)d_in[2];
    float* out = (float*)d_out;

    const int nseq = in_sizes[1];       // 8*2*257 = 4112

    int G = (nseq + 3) / 4;             // ns = 4 uniform for 4112 -> 1028 blocks
    if (G < 1) G = 1;
    if (G > nseq) G = nseq;

    ema_kernel<<<G, BLOCK, 0, stream>>>(mag_spec, initial_state, weights, out, nseq);
}